// Round 1
// baseline (463.742 us; speedup 1.0000x reference)
//
#include <hip/hip_runtime.h>
#include <math.h>

#define Bq 8
#define Lq 16384
#define Hq 64
#define N2q 32
#define NLAYERSq 5

#define STH 512              // scan kernel threads per WG
#define NGR (STH/4)          // 128 chunks per (b,h)
#define LCq (Lq/NGR)         // 128 steps per chunk

__device__ __forceinline__ float fast_tanh(float y) {
    // tanh(y) = 1 - 2/(exp(2y)+1); exp overflow/underflow saturate correctly
    float e = __expf(2.0f * y);
    return 1.0f - 2.0f * __builtin_amdgcn_rcpf(e + 1.0f);
}

// ---------------------------------------------------------------------------
// K1: u[b,h,l] = tanh( 20*log10(|x[b,l]|+eps) * w_in[h] + b_in[h] )
// ---------------------------------------------------------------------------
__global__ __launch_bounds__(256)
void k_input(const float* __restrict__ x, const float* __restrict__ w_in,
             const float* __restrict__ b_in, float* __restrict__ u) {
    int idx = blockIdx.x * 256 + threadIdx.x;       // over B*H*L, l fastest
    int l  = idx & (Lq - 1);
    int bh = idx >> 14;
    int h  = bh & (Hq - 1);
    int b  = bh >> 6;
    float xv = x[(b << 14) + l];
    float s  = 6.0205999132796239f * __log2f(fabsf(xv) + 1e-5f); // 20*log10
    u[idx] = fast_tanh(fmaf(s, w_in[h], b_in[h]));
}

// ---------------------------------------------------------------------------
// K2: DSSM scan + tanh.  One WG per (b,h). Two-sweep chunk-parallel scan.
// ---------------------------------------------------------------------------
__global__ __launch_bounds__(STH)
void k_scan(const float* __restrict__ uin, float* __restrict__ uout,
            const float* __restrict__ log_dt, const float* __restrict__ log_A_real,
            const float* __restrict__ A_imag, const float* __restrict__ C_re,
            const float* __restrict__ C_im, const float* __restrict__ Dvec,
            int layer) {
    __shared__ float mw[N2q][2];    // w = exp(dtA)
    __shared__ float mc[N2q][2];    // c = C*(exp(dtA)-1)/A
    __shared__ float mwL[N2q][2];   // w^LC
    __shared__ float st[NGR][N2q][2];

    const int bh  = blockIdx.x;
    const int h   = bh & (Hq - 1);
    const int tid = threadIdx.x;

    if (tid < N2q) {
        int n = tid;
        int pidx = (layer * Hq + h) * N2q + n;
        double dt  = exp((double)log_dt[layer * Hq + h]);
        double aRe = -exp((double)log_A_real[pidx]);
        double aIm = (double)A_imag[pidx];
        double dAr = aRe * dt, dAi = aIm * dt;
        double er  = exp(dAr);
        double wre = er * cos(dAi), wim = er * sin(dAi);
        double Er  = wre - 1.0, Ei = wim;          // exp(dtA)-1
        double inv = 1.0 / (aRe * aRe + aIm * aIm);
        double Fr  = (Er * aRe + Ei * aIm) * inv;  // (exp(dtA)-1)/A
        double Fi  = (Ei * aRe - Er * aIm) * inv;
        double Cr  = (double)C_re[pidx], Ci = (double)C_im[pidx];
        mw[n][0] = (float)wre;            mw[n][1] = (float)wim;
        mc[n][0] = (float)(Cr * Fr - Ci * Fi);
        mc[n][1] = (float)(Cr * Fi + Ci * Fr);
        double eL  = exp(dAr * (double)LCq);
        double phL = dAi * (double)LCq;
        mwL[n][0] = (float)(eL * cos(phL));
        mwL[n][1] = (float)(eL * sin(phL));
    }
    __syncthreads();

    const int g = tid >> 2;     // chunk id (0..127)
    const int r = tid & 3;      // mode sub-group: modes r*8 .. r*8+7

    float wr[8], wi[8], cr[8], ci[8], sr[8], si[8];
    #pragma unroll
    for (int m = 0; m < 8; m++) {
        int n = (r << 3) | m;
        wr[m] = mw[n][0]; wi[m] = mw[n][1];
        cr[m] = mc[n][0]; ci[m] = mc[n][1];
        sr[m] = 0.f; si[m] = 0.f;
    }

    const float* up = uin + ((size_t)bh << 14) + (g << 7);

    // ---- sweep 1: zero-init local chunk scan -> final states ----
    for (int i = 0; i < LCq; i += 4) {
        float4 u4 = *(const float4*)(up + i);
        float uu[4] = {u4.x, u4.y, u4.z, u4.w};
        #pragma unroll
        for (int k = 0; k < 4; k++) {
            float uv = uu[k];
            #pragma unroll
            for (int m = 0; m < 8; m++) {
                float nr = fmaf(wr[m], sr[m], fmaf(-wi[m], si[m], uv));
                si[m] = fmaf(wr[m], si[m], wi[m] * sr[m]);
                sr[m] = nr;
            }
        }
    }
    #pragma unroll
    for (int m = 0; m < 8; m++) {
        int n = (r << 3) | m;
        st[g][n][0] = sr[m]; st[g][n][1] = si[m];
    }
    __syncthreads();

    // ---- cross-chunk serial scan (32 lanes, in-place: slot j becomes S_j) ----
    if (tid < N2q) {
        int n = tid;
        float wLr = mwL[n][0], wLi = mwL[n][1];
        float Sr = 0.f, Si = 0.f;
        for (int j = 0; j < NGR; j++) {
            float fr = st[j][n][0], fi = st[j][n][1];
            st[j][n][0] = Sr; st[j][n][1] = Si;
            float nSr = fmaf(wLr, Sr, fmaf(-wLi, Si, fr));
            Si = fmaf(wLr, Si, fmaf(wLi, Sr, fi));
            Sr = nSr;
        }
    }
    __syncthreads();

    // ---- sweep 2: replay with true initial state, emit tanh(y) ----
    #pragma unroll
    for (int m = 0; m < 8; m++) {
        int n = (r << 3) | m;
        sr[m] = st[g][n][0]; si[m] = st[g][n][1];
    }
    const float Du = Dvec[layer * Hq + h];
    float* yp = uout + ((size_t)bh << 14) + (g << 7);

    for (int i = 0; i < LCq; i += 4) {
        float4 u4 = *(const float4*)(up + i);
        float uu[4] = {u4.x, u4.y, u4.z, u4.w};
        float o4[4];
        #pragma unroll
        for (int k = 0; k < 4; k++) {
            float uv = uu[k];
            float acc = 0.f;
            #pragma unroll
            for (int m = 0; m < 8; m++) {
                float nr = fmaf(wr[m], sr[m], fmaf(-wi[m], si[m], uv));
                si[m] = fmaf(wr[m], si[m], wi[m] * sr[m]);
                sr[m] = nr;
                acc = fmaf(cr[m], sr[m], acc);
                acc = fmaf(-ci[m], si[m], acc);
            }
            acc += __shfl_xor(acc, 1);   // sum 32 modes across the 4-lane group
            acc += __shfl_xor(acc, 2);
            o4[k] = fast_tanh(fmaf(Du, uv, acc + acc));
        }
        if (r == 0) {
            *(float4*)(yp + i) = make_float4(o4[0], o4[1], o4[2], o4[3]);
        }
    }
}

// ---------------------------------------------------------------------------
// K3: channel-major linear + tanh: out[b,o,l] = tanh(b[o] + sum_h W[o,h]*u[b,h,l])
// ---------------------------------------------------------------------------
__global__ __launch_bounds__(256)
void k_linear(const float* __restrict__ uin, const float* __restrict__ W,
              const float* __restrict__ bias, float* __restrict__ uout) {
    __shared__ float Wt[64][68];   // transposed: Wt[h][o], padded rows (272B, 16B-aligned)
    __shared__ float Ut[64][64];   // Ut[h][ll]
    const int b  = blockIdx.y;
    const int l0 = blockIdx.x * 64;
    const int tid = threadIdx.x;

    for (int idx = tid; idx < 4096; idx += 256) {
        int o = idx >> 6, hh = idx & 63;
        Wt[hh][o] = W[idx];
        Ut[o][hh] = uin[(((size_t)(b << 6) | o) << 14) + l0 + hh]; // o==h row, hh==ll
    }
    __syncthreads();

    float acc[4][4];
    #pragma unroll
    for (int j = 0; j < 4; j++)
        #pragma unroll
        for (int k = 0; k < 4; k++) acc[j][k] = 0.f;

    const int og = (tid >> 4) << 2;
    const int lg = (tid & 15) << 2;

    #pragma unroll 4
    for (int hh = 0; hh < 64; ++hh) {
        float4 wv = *(const float4*)&Wt[hh][og];
        float4 uv = *(const float4*)&Ut[hh][lg];
        acc[0][0] = fmaf(wv.x, uv.x, acc[0][0]); acc[0][1] = fmaf(wv.x, uv.y, acc[0][1]);
        acc[0][2] = fmaf(wv.x, uv.z, acc[0][2]); acc[0][3] = fmaf(wv.x, uv.w, acc[0][3]);
        acc[1][0] = fmaf(wv.y, uv.x, acc[1][0]); acc[1][1] = fmaf(wv.y, uv.y, acc[1][1]);
        acc[1][2] = fmaf(wv.y, uv.z, acc[1][2]); acc[1][3] = fmaf(wv.y, uv.w, acc[1][3]);
        acc[2][0] = fmaf(wv.z, uv.x, acc[2][0]); acc[2][1] = fmaf(wv.z, uv.y, acc[2][1]);
        acc[2][2] = fmaf(wv.z, uv.z, acc[2][2]); acc[2][3] = fmaf(wv.z, uv.w, acc[2][3]);
        acc[3][0] = fmaf(wv.w, uv.x, acc[3][0]); acc[3][1] = fmaf(wv.w, uv.y, acc[3][1]);
        acc[3][2] = fmaf(wv.w, uv.z, acc[3][2]); acc[3][3] = fmaf(wv.w, uv.w, acc[3][3]);
    }

    #pragma unroll
    for (int j = 0; j < 4; j++) {
        float bo = bias[og + j];
        float4 o4;
        o4.x = fast_tanh(acc[j][0] + bo);
        o4.y = fast_tanh(acc[j][1] + bo);
        o4.z = fast_tanh(acc[j][2] + bo);
        o4.w = fast_tanh(acc[j][3] + bo);
        *(float4*)&uout[(((size_t)(b << 6) | (og + j)) << 14) + l0 + lg] = o4;
    }
}

// ---------------------------------------------------------------------------
// K4: out[b,l] = x[b,l] * 10^((sum_h w_out[h]*u[b,h,l] + b_out)/20)
// ---------------------------------------------------------------------------
__global__ __launch_bounds__(256)
void k_out(const float* __restrict__ u, const float* __restrict__ x,
           const float* __restrict__ w_out, const float* __restrict__ b_out,
           float* __restrict__ out) {
    int idx = blockIdx.x * 256 + threadIdx.x;   // over B*L
    int b = idx >> 14;
    int l = idx & (Lq - 1);
    const float* up = u + ((size_t)b << 20) + l;
    float acc = 0.f;
    #pragma unroll 8
    for (int hh = 0; hh < 64; ++hh)
        acc = fmaf(w_out[hh], up[(size_t)hh << 14], acc);
    float g = acc + b_out[0];
    out[idx] = x[idx] * exp2f(g * 0.16609640474436812f);  // log2(10)/20
}

// ---------------------------------------------------------------------------
extern "C" void kernel_launch(void* const* d_in, const int* in_sizes, int n_in,
                              void* d_out, int out_size, void* d_ws, size_t ws_size,
                              hipStream_t stream) {
    const float* x          = (const float*)d_in[0];
    const float* w_in       = (const float*)d_in[1];
    const float* b_in       = (const float*)d_in[2];
    const float* w_mid      = (const float*)d_in[3];
    const float* b_mid      = (const float*)d_in[4];
    const float* w_out      = (const float*)d_in[5];
    const float* b_out      = (const float*)d_in[6];
    const float* log_dt     = (const float*)d_in[7];
    const float* log_A_real = (const float*)d_in[8];
    const float* A_imag     = (const float*)d_in[9];
    const float* C_re       = (const float*)d_in[10];
    const float* C_im       = (const float*)d_in[11];
    const float* Dv         = (const float*)d_in[12];

    float* u0 = (float*)d_ws;
    float* u1 = u0 + (size_t)Bq * Hq * Lq;
    float* out = (float*)d_out;

    k_input<<<(Bq * Hq * Lq) / 256, 256, 0, stream>>>(x, w_in, b_in, u0);
    k_scan<<<Bq * Hq, STH, 0, stream>>>(u0, u1, log_dt, log_A_real, A_imag,
                                        C_re, C_im, Dv, 0);
    for (int i = 0; i < 4; i++) {
        k_linear<<<dim3(Lq / 64, Bq), 256, 0, stream>>>(
            u1, w_mid + (size_t)i * Hq * Hq, b_mid + (size_t)i * Hq, u0);
        k_scan<<<Bq * Hq, STH, 0, stream>>>(u0, u1, log_dt, log_A_real, A_imag,
                                            C_re, C_im, Dv, i + 1);
    }
    k_out<<<(Bq * Lq) / 256, 256, 0, stream>>>(u1, x, w_out, b_out, out);
}

// Round 2
// 433.270 us; speedup vs baseline: 1.0703x; 1.0703x over previous
//
#include <hip/hip_runtime.h>
#include <math.h>

#define Bq 8
#define Lq 16384
#define Hq 64
#define N2q 32
#define NLAYERSq 5

#define STH 512              // scan kernel threads per WG
#define NGR (STH/4)          // 128 chunks per (b,h)
#define LCq (Lq/NGR)         // 128 steps per chunk

typedef float v2f __attribute__((ext_vector_type(2)));

__device__ __forceinline__ float fast_tanh(float y) {
    float e = __expf(2.0f * y);
    return 1.0f - 2.0f * __builtin_amdgcn_rcpf(e + 1.0f);
}

// ---------------------------------------------------------------------------
// K1: u[b,h,l] = tanh( 20*log10(|x[b,l]|+eps) * w_in[h] + b_in[h] )
// ---------------------------------------------------------------------------
__global__ __launch_bounds__(256)
void k_input(const float* __restrict__ x, const float* __restrict__ w_in,
             const float* __restrict__ b_in, float* __restrict__ u) {
    int idx = blockIdx.x * 256 + threadIdx.x;       // over B*H*L, l fastest
    int l  = idx & (Lq - 1);
    int bh = idx >> 14;
    int h  = bh & (Hq - 1);
    int b  = bh >> 6;
    float xv = x[(b << 14) + l];
    float s  = 6.0205999132796239f * __log2f(fabsf(xv) + 1e-5f); // 20*log10
    u[idx] = fast_tanh(fmaf(s, w_in[h], b_in[h]));
}

// ---------------------------------------------------------------------------
// K2: DSSM scan + tanh.  One WG per (b,h). Two-sweep chunk-parallel scan.
// Modes packed in pairs (v2f) so the whole inner loop is v_pk_fma_f32.
// ---------------------------------------------------------------------------
__global__ __launch_bounds__(STH)
void k_scan(const float* __restrict__ uin, float* __restrict__ uout,
            const float* __restrict__ log_dt, const float* __restrict__ log_A_real,
            const float* __restrict__ A_imag, const float* __restrict__ C_re,
            const float* __restrict__ C_im, const float* __restrict__ Dvec,
            int layer) {
    __shared__ float mw[N2q][2];    // w = exp(dtA)
    __shared__ float mc[N2q][2];    // 2 * C*(exp(dtA)-1)/A   (factor 2 folded)
    __shared__ float mwL[N2q][2];   // w^LC
    __shared__ float st[NGR][N2q][2];

    const int bh  = blockIdx.x;
    const int h   = bh & (Hq - 1);
    const int tid = threadIdx.x;

    if (tid < N2q) {
        int n = tid;
        int pidx = (layer * Hq + h) * N2q + n;
        double dt  = exp((double)log_dt[layer * Hq + h]);
        double aRe = -exp((double)log_A_real[pidx]);
        double aIm = (double)A_imag[pidx];
        double dAr = aRe * dt, dAi = aIm * dt;
        double er  = exp(dAr);
        double wre = er * cos(dAi), wim = er * sin(dAi);
        double Er  = wre - 1.0, Ei = wim;          // exp(dtA)-1
        double inv = 1.0 / (aRe * aRe + aIm * aIm);
        double Fr  = (Er * aRe + Ei * aIm) * inv;  // (exp(dtA)-1)/A
        double Fi  = (Ei * aRe - Er * aIm) * inv;
        double Cr  = (double)C_re[pidx], Ci = (double)C_im[pidx];
        mw[n][0] = (float)wre;            mw[n][1] = (float)wim;
        mc[n][0] = (float)(2.0 * (Cr * Fr - Ci * Fi));
        mc[n][1] = (float)(2.0 * (Cr * Fi + Ci * Fr));
        double eL  = exp(dAr * (double)LCq);
        double phL = dAi * (double)LCq;
        mwL[n][0] = (float)(eL * cos(phL));
        mwL[n][1] = (float)(eL * sin(phL));
    }
    __syncthreads();

    const int g = tid >> 2;     // chunk id (0..127)
    const int r = tid & 3;      // mode sub-group: modes r*8 .. r*8+7 (4 pairs)

    v2f wR[4], wI[4], wIn[4], cR[4], cIn[4], sR[4], sI[4];
    #pragma unroll
    for (int p = 0; p < 4; p++) {
        int n0 = (r << 3) | (p << 1);
        wR[p]  = (v2f){mw[n0][0], mw[n0 + 1][0]};
        wI[p]  = (v2f){mw[n0][1], mw[n0 + 1][1]};
        wIn[p] = -wI[p];
        cR[p]  = (v2f){mc[n0][0], mc[n0 + 1][0]};
        cIn[p] = (v2f){-mc[n0][1], -mc[n0 + 1][1]};
        sR[p]  = (v2f){0.f, 0.f};
        sI[p]  = (v2f){0.f, 0.f};
    }

    const float* up = uin + ((size_t)bh << 14) + (g << 7);

    // ---- sweep 1: zero-init local chunk scan -> final states ----
    for (int i = 0; i < LCq; i += 4) {
        float4 u4 = *(const float4*)(up + i);
        float uu[4] = {u4.x, u4.y, u4.z, u4.w};
        #pragma unroll
        for (int k = 0; k < 4; k++) {
            v2f uvv = (v2f){uu[k], uu[k]};
            #pragma unroll
            for (int p = 0; p < 4; p++) {
                v2f t  = __builtin_elementwise_fma(wIn[p], sI[p], uvv);
                v2f tI = wI[p] * sR[p];
                sR[p] = __builtin_elementwise_fma(wR[p], sR[p], t);
                sI[p] = __builtin_elementwise_fma(wR[p], sI[p], tI);
            }
        }
    }
    #pragma unroll
    for (int p = 0; p < 4; p++) {
        int n0 = (r << 3) | (p << 1);
        st[g][n0][0]     = sR[p].x; st[g][n0][1]     = sI[p].x;
        st[g][n0 + 1][0] = sR[p].y; st[g][n0 + 1][1] = sI[p].y;
    }
    __syncthreads();

    // ---- cross-chunk serial scan (32 lanes, in-place: slot j becomes S_j) ----
    if (tid < N2q) {
        int n = tid;
        float wLr = mwL[n][0], wLi = mwL[n][1];
        float Sr = 0.f, Si = 0.f;
        float fr = st[0][n][0], fi = st[0][n][1];
        #pragma unroll 4
        for (int j = 0; j < NGR; j++) {
            float fr2 = 0.f, fi2 = 0.f;
            if (j + 1 < NGR) { fr2 = st[j + 1][n][0]; fi2 = st[j + 1][n][1]; }
            st[j][n][0] = Sr; st[j][n][1] = Si;
            float nSr = fmaf(wLr, Sr, fmaf(-wLi, Si, fr));
            Si = fmaf(wLr, Si, fmaf(wLi, Sr, fi));
            Sr = nSr;
            fr = fr2; fi = fi2;
        }
    }
    __syncthreads();

    // ---- sweep 2: replay with true initial state, emit tanh(y) ----
    #pragma unroll
    for (int p = 0; p < 4; p++) {
        int n0 = (r << 3) | (p << 1);
        sR[p] = (v2f){st[g][n0][0], st[g][n0 + 1][0]};
        sI[p] = (v2f){st[g][n0][1], st[g][n0 + 1][1]};
    }
    const float Du = Dvec[layer * Hq + h];
    float* yp = uout + ((size_t)bh << 14) + (g << 7);

    for (int i = 0; i < LCq; i += 4) {
        float4 u4 = *(const float4*)(up + i);
        float uu[4] = {u4.x, u4.y, u4.z, u4.w};
        float o4[4];
        #pragma unroll
        for (int k = 0; k < 4; k++) {
            v2f uvv = (v2f){uu[k], uu[k]};
            v2f accP = (v2f){0.f, 0.f};
            #pragma unroll
            for (int p = 0; p < 4; p++) {
                v2f t  = __builtin_elementwise_fma(wIn[p], sI[p], uvv);
                v2f tI = wI[p] * sR[p];
                sR[p] = __builtin_elementwise_fma(wR[p], sR[p], t);
                sI[p] = __builtin_elementwise_fma(wR[p], sI[p], tI);
                accP = __builtin_elementwise_fma(cR[p],  sR[p], accP);
                accP = __builtin_elementwise_fma(cIn[p], sI[p], accP);
            }
            float acc = accP.x + accP.y;   // 2x already folded into c
            acc += __shfl_xor(acc, 1);     // sum 32 modes across the 4-lane group
            acc += __shfl_xor(acc, 2);
            o4[k] = fast_tanh(fmaf(Du, uu[k], acc));
        }
        if (r == 0) {
            *(float4*)(yp + i) = make_float4(o4[0], o4[1], o4[2], o4[3]);
        }
    }
}

// ---------------------------------------------------------------------------
// K3: channel-major linear + tanh: out[b,o,l] = tanh(b[o] + sum_h W[o,h]*u[b,h,l])
// ---------------------------------------------------------------------------
__global__ __launch_bounds__(256)
void k_linear(const float* __restrict__ uin, const float* __restrict__ W,
              const float* __restrict__ bias, float* __restrict__ uout) {
    __shared__ float Wt[64][68];   // transposed: Wt[h][o]
    __shared__ float Ut[64][64];   // Ut[h][ll]
    const int b  = blockIdx.y;
    const int l0 = blockIdx.x * 64;
    const int tid = threadIdx.x;

    for (int idx = tid; idx < 4096; idx += 256) {
        int o = idx >> 6, hh = idx & 63;
        Wt[hh][o] = W[idx];
        Ut[o][hh] = uin[(((size_t)(b << 6) | o) << 14) + l0 + hh];
    }
    __syncthreads();

    float acc[4][4];
    #pragma unroll
    for (int j = 0; j < 4; j++)
        #pragma unroll
        for (int k = 0; k < 4; k++) acc[j][k] = 0.f;

    const int og = (tid >> 4) << 2;
    const int lg = (tid & 15) << 2;

    #pragma unroll 4
    for (int hh = 0; hh < 64; ++hh) {
        float4 wv = *(const float4*)&Wt[hh][og];
        float4 uv = *(const float4*)&Ut[hh][lg];
        acc[0][0] = fmaf(wv.x, uv.x, acc[0][0]); acc[0][1] = fmaf(wv.x, uv.y, acc[0][1]);
        acc[0][2] = fmaf(wv.x, uv.z, acc[0][2]); acc[0][3] = fmaf(wv.x, uv.w, acc[0][3]);
        acc[1][0] = fmaf(wv.y, uv.x, acc[1][0]); acc[1][1] = fmaf(wv.y, uv.y, acc[1][1]);
        acc[1][2] = fmaf(wv.y, uv.z, acc[1][2]); acc[1][3] = fmaf(wv.y, uv.w, acc[1][3]);
        acc[2][0] = fmaf(wv.z, uv.x, acc[2][0]); acc[2][1] = fmaf(wv.z, uv.y, acc[2][1]);
        acc[2][2] = fmaf(wv.z, uv.z, acc[2][2]); acc[2][3] = fmaf(wv.z, uv.w, acc[2][3]);
        acc[3][0] = fmaf(wv.w, uv.x, acc[3][0]); acc[3][1] = fmaf(wv.w, uv.y, acc[3][1]);
        acc[3][2] = fmaf(wv.w, uv.z, acc[3][2]); acc[3][3] = fmaf(wv.w, uv.w, acc[3][3]);
    }

    #pragma unroll
    for (int j = 0; j < 4; j++) {
        float bo = bias[og + j];
        float4 o4;
        o4.x = fast_tanh(acc[j][0] + bo);
        o4.y = fast_tanh(acc[j][1] + bo);
        o4.z = fast_tanh(acc[j][2] + bo);
        o4.w = fast_tanh(acc[j][3] + bo);
        *(float4*)&uout[(((size_t)(b << 6) | (og + j)) << 14) + l0 + lg] = o4;
    }
}

// ---------------------------------------------------------------------------
// K4: out[b,l] = x[b,l] * 10^((sum_h w_out[h]*u[b,h,l] + b_out)/20)
// ---------------------------------------------------------------------------
__global__ __launch_bounds__(256)
void k_out(const float* __restrict__ u, const float* __restrict__ x,
           const float* __restrict__ w_out, const float* __restrict__ b_out,
           float* __restrict__ out) {
    int idx = blockIdx.x * 256 + threadIdx.x;   // over B*L
    int b = idx >> 14;
    int l = idx & (Lq - 1);
    const float* up = u + ((size_t)b << 20) + l;
    float acc = 0.f;
    #pragma unroll 8
    for (int hh = 0; hh < 64; ++hh)
        acc = fmaf(w_out[hh], up[(size_t)hh << 14], acc);
    float g = acc + b_out[0];
    out[idx] = x[idx] * exp2f(g * 0.16609640474436812f);  // log2(10)/20
}

// ---------------------------------------------------------------------------
extern "C" void kernel_launch(void* const* d_in, const int* in_sizes, int n_in,
                              void* d_out, int out_size, void* d_ws, size_t ws_size,
                              hipStream_t stream) {
    const float* x          = (const float*)d_in[0];
    const float* w_in       = (const float*)d_in[1];
    const float* b_in       = (const float*)d_in[2];
    const float* w_mid      = (const float*)d_in[3];
    const float* b_mid      = (const float*)d_in[4];
    const float* w_out      = (const float*)d_in[5];
    const float* b_out      = (const float*)d_in[6];
    const float* log_dt     = (const float*)d_in[7];
    const float* log_A_real = (const float*)d_in[8];
    const float* A_imag     = (const float*)d_in[9];
    const float* C_re       = (const float*)d_in[10];
    const float* C_im       = (const float*)d_in[11];
    const float* Dv         = (const float*)d_in[12];

    float* u0 = (float*)d_ws;
    float* u1 = u0 + (size_t)Bq * Hq * Lq;
    float* out = (float*)d_out;

    k_input<<<(Bq * Hq * Lq) / 256, 256, 0, stream>>>(x, w_in, b_in, u0);
    k_scan<<<Bq * Hq, STH, 0, stream>>>(u0, u1, log_dt, log_A_real, A_imag,
                                        C_re, C_im, Dv, 0);
    for (int i = 0; i < 4; i++) {
        k_linear<<<dim3(Lq / 64, Bq), 256, 0, stream>>>(
            u1, w_mid + (size_t)i * Hq * Hq, b_mid + (size_t)i * Hq, u0);
        k_scan<<<Bq * Hq, STH, 0, stream>>>(u0, u1, log_dt, log_A_real, A_imag,
                                            C_re, C_im, Dv, i + 1);
    }
    k_out<<<(Bq * Lq) / 256, 256, 0, stream>>>(u1, x, w_out, b_out, out);
}